// Round 2
// baseline (8105.994 us; speedup 1.0000x reference)
//
#include <hip/hip_runtime.h>
#include <stdint.h>

typedef unsigned long long u64;
typedef uint32_t u32;

#define VOCAB 128
#define RD 128
#define DM 1024
#define NFF 6
#define BATCH 64
#define TSTEPS 512
#define NLOC 3    // layers per pipeline stage
#define HALF 512  // threads per block; each thread owns cols tid and tid+512

// ---------------------------------------------------------------------------
// ws layout (bytes):
//   [0,        786432)  ffbits [L][w][j] u64  (L<6, w<16, j<1024)
//   [786432,  +2048)    ebits  [v][2]    u64
//   [788480,  +2048)    headb  [v][2]    u64
//   [790528,  +512)     losses [64]      double
//   [791040,  +8192)    xbuf   [64][16]  u64  (x for next step, written by B)
//   [799232,  +8192)    mbuf   [64][16]  u64  (mid h after layer 2, by A)
//   [807424,  +256)     fA     [64]      u32  (A published mid for step t -> t+1)
//   [807680,  +256)     fB     [64]      u32  (B completed step t -> t+1)
// ---------------------------------------------------------------------------
#define OFF_EB    786432
#define OFF_HB    788480
#define OFF_LOSS  790528
#define OFF_XBUF  791040
#define OFF_MBUF  799232
#define OFF_FA    807424
#define OFF_FB    807680

__device__ __forceinline__ void wait_ge(const u32* f, u32 target) {
    while (__hip_atomic_load(f, __ATOMIC_ACQUIRE, __HIP_MEMORY_SCOPE_AGENT) < target)
        __builtin_amdgcn_s_sleep(1);
}

// Pack ff sign bits: bit b of word (L,w,j) = (ff[L][w*64+b][j] < 0)  (1 => -1)
__global__ void pack_ff(const float* __restrict__ ff, u64* __restrict__ ffb) {
    int wid  = blockIdx.x * (blockDim.x >> 6) + (threadIdx.x >> 6); // 0..1535
    int lane = threadIdx.x & 63;
    int jt = wid & 15;
    int w  = (wid >> 4) & 15;
    int i  = wid >> 8;
    int j  = jt * 64 + lane;
    const float* src = ff + ((size_t)(i * DM) + w * 64) * DM + j;
    u64 word = 0;
#pragma unroll
    for (int b = 0; b < 64; ++b) {
        float v = src[(size_t)b * DM];
        word |= (u64)(v < 0.0f) << b;
    }
    ffb[((i * 16 + w) << 10) + j] = word;
}

__global__ void pack_small(const float* __restrict__ emb, const float* __restrict__ head,
                           u64* __restrict__ eb, u64* __restrict__ hb) {
    int tid = threadIdx.x; // 0..255
    if (tid < 128) {
        int v = tid;
        for (int wd = 0; wd < 2; ++wd) {
            u64 word = 0;
            for (int l = 0; l < 64; ++l)
                word |= (u64)(emb[v * RD + wd * 64 + l] < 0.0f) << l;
            eb[v * 2 + wd] = word;
        }
    } else {
        int v = tid - 128;
        for (int wd = 0; wd < 2; ++wd) {
            u64 word = 0;
            for (int l = 0; l < 64; ++l)
                word |= (u64)(head[(wd * 64 + l) * VOCAB + v] < 0.0f) << l;
            hb[v * 2 + wd] = word;
        }
    }
}

// Pipelined main kernel: 64 blocks x 512 threads.
// Blocks 0..31  = stage A (layers 0-2) for rows {2g, 2g+1}
// Blocks 32..63 = stage B (layers 3-5 + head/loss/splice) for rows {2g, 2g+1}
// Each thread owns output columns tid and tid+512; weights for its 3 layers
// (192 VGPRs) stay register-resident (cap 256 via __launch_bounds__(512,2)).
__global__ void __launch_bounds__(512, 2)
brnn_pipe(const int* __restrict__ tokens,
          const float* __restrict__ initial_lat,
          const float* __restrict__ thr_lat,
          const u64* __restrict__ ffb,
          const u64* __restrict__ eb,
          const u64* __restrict__ hb,
          u64* __restrict__ xbuf, u64* __restrict__ mbuf,
          u32* __restrict__ fA, u32* __restrict__ fB,
          double* __restrict__ losses)
{
    const int blk  = blockIdx.x;
    const int role = blk >> 5; // 0 = A, 1 = B
    const int g    = blk & 31;
    const int tid  = threadIdx.x;
    const int lane = tid & 63;
    const int wv   = tid >> 6; // 0..7

    __shared__ __align__(16) u64 hx[2][16];
    __shared__ u64 hbL[VOCAB][2];

    const int lbase = role * NLOC;

    // resident packed weights: 2 cols x 3 layers x 16 words = 192 VGPRs
    u64 fa[NLOC][16], fb[NLOC][16];
#pragma unroll
    for (int i = 0; i < NLOC; ++i)
#pragma unroll
        for (int w = 0; w < 16; ++w) {
            fa[i][w] = ffb[(((lbase + i) * 16 + w) << 10) + tid];
            fb[i][w] = ffb[(((lbase + i) * 16 + w) << 10) + tid + HALF];
        }

    int cthrA[NLOC], cthrB[NLOC];
#pragma unroll
    for (int i = 0; i < NLOC; ++i) {
        int ta = (int)rintf(thr_lat[(lbase + i) * DM + tid]);
        int tb = (int)rintf(thr_lat[(lbase + i) * DM + tid + HALF]);
        cthrA[i] = ((DM - ta) >> 1) + 1; // bit(-1) <=> popcnt >= cthr
        cthrB[i] = ((DM - tb) >> 1) + 1;
    }

    if (role == 1 && tid < 256) ((u64*)hbL)[tid] = hb[tid];

    double lacc0 = 0.0, lacc1 = 0.0;
    const int r0 = 2 * g;

    if (role == 0) {
        // ------------------------- stage A: layers 0-2 -------------------------
        for (int t = 0; t < TSTEPS; ++t) {
#pragma unroll
            for (int ri = 0; ri < 2; ++ri) {
                const int r = r0 + ri;
                if (t == 0) {
                    u64 m0 = __ballot(initial_lat[tid] < 0.0f);
                    u64 m1 = __ballot(initial_lat[tid + HALF] < 0.0f);
                    if (lane == 0) { hx[0][wv] = m0; hx[0][wv + 8] = m1; }
                } else {
                    wait_ge(&fB[r], (u32)t); // acquire: invalidates L1, xbuf fresh
                    if (wv == 0 && lane < 16) hx[0][lane] = xbuf[r * 16 + lane];
                }
                __syncthreads();
                int p = 0;
#pragma unroll
                for (int i = 0; i < NLOC; ++i) {
                    const ulonglong2* hp = (const ulonglong2*)hx[p];
                    int a0 = 0, a1 = 0;
#pragma unroll
                    for (int q = 0; q < 8; ++q) {
                        ulonglong2 hv = hp[q]; // broadcast ds_read_b128
                        a0 += __popcll(hv.x ^ fa[i][2 * q]) + __popcll(hv.y ^ fa[i][2 * q + 1]);
                        a1 += __popcll(hv.x ^ fb[i][2 * q]) + __popcll(hv.y ^ fb[i][2 * q + 1]);
                    }
                    u64 m0 = __ballot(a0 >= cthrA[i]);
                    u64 m1 = __ballot(a1 >= cthrB[i]);
                    if (i < NLOC - 1) {
                        if (lane == 0) { hx[p ^ 1][wv] = m0; hx[p ^ 1][wv + 8] = m1; }
                    } else {
                        if (lane == 0) { mbuf[r * 16 + wv] = m0; mbuf[r * 16 + 8 + wv] = m1; }
                    }
                    __syncthreads(); // also drains the global stores (vmcnt 0)
                    p ^= 1;
                }
                if (tid == 0)
                    __hip_atomic_store(&fA[r], (u32)(t + 1), __ATOMIC_RELEASE,
                                       __HIP_MEMORY_SCOPE_AGENT);
            }
        }
    } else {
        // ---------------- stage B: layers 3-5 + head + splice ----------------
        for (int t = 0; t < TSTEPS; ++t) {
#pragma unroll
            for (int ri = 0; ri < 2; ++ri) {
                const int r = r0 + ri;
                wait_ge(&fA[r], (u32)(t + 1));
                const int tok = tokens[r * TSTEPS + t]; // uniform scalar load
                u64 enew = 0;
                if (wv == 0 && lane < 2) enew = eb[tok * 2 + lane]; // prefetch
                if (wv == 0 && lane < 16) hx[0][lane] = mbuf[r * 16 + lane];
                __syncthreads();
                int p = 0;
#pragma unroll
                for (int i = 0; i < NLOC; ++i) {
                    const ulonglong2* hp = (const ulonglong2*)hx[p];
                    int a0 = 0, a1 = 0;
#pragma unroll
                    for (int q = 0; q < 8; ++q) {
                        ulonglong2 hv = hp[q];
                        a0 += __popcll(hv.x ^ fa[i][2 * q]) + __popcll(hv.y ^ fa[i][2 * q + 1]);
                        a1 += __popcll(hv.x ^ fb[i][2 * q]) + __popcll(hv.y ^ fb[i][2 * q + 1]);
                    }
                    u64 m0 = __ballot(a0 >= cthrA[i]);
                    u64 m1 = __ballot(a1 >= cthrB[i]);
                    if (i < NLOC - 1) {
                        if (lane == 0) { hx[p ^ 1][wv] = m0; hx[p ^ 1][wv + 8] = m1; }
                    } else {
                        if (lane == 0) {
                            hx[p ^ 1][wv] = m0; hx[p ^ 1][wv + 8] = m1; // for head
                            xbuf[r * 16 + wv] = m0;                // carry words 0-7
                            if (wv < 6) xbuf[r * 16 + 8 + wv] = m1; // carry words 8-13
                        }
                    }
                    __syncthreads();
                    p ^= 1;
                }
                // head + log-softmax + loss + embed splice (wave 0); h5 in hx[1]
                if (wv == 0) {
                    u64 ra = hx[1][14], rb = hx[1][15];
                    u64 h0a = hbL[lane][0],      h0b = hbL[lane][1];
                    u64 h1a = hbL[lane + 64][0], h1b = hbL[lane + 64][1];
                    int d0 = 128 - 2 * (__popcll(ra ^ h0a) + __popcll(rb ^ h0b));
                    int d1 = 128 - 2 * (__popcll(ra ^ h1a) + __popcll(rb ^ h1b));
                    float l0 = (float)d0 * (1.0f / 16.0f);
                    float l1 = (float)d1 * (1.0f / 16.0f);
                    float mx = fmaxf(l0, l1);
#pragma unroll
                    for (int s = 32; s >= 1; s >>= 1) mx = fmaxf(mx, __shfl_xor(mx, s));
                    float se = __expf(l0 - mx) + __expf(l1 - mx);
#pragma unroll
                    for (int s = 32; s >= 1; s >>= 1) se += __shfl_xor(se, s);
                    int   tl   = tok & 63;
                    float la   = __shfl(l0, tl);
                    float lb_  = __shfl(l1, tl);
                    float ltok = (tok >> 6) ? lb_ : la;
                    double dl = (double)(mx + __logf(se) - ltok);
                    if (ri == 0) lacc0 += dl; else lacc1 += dl;
                    if (lane < 2) xbuf[r * 16 + 14 + lane] = enew; // read-part splice
                }
                __syncthreads(); // drain wave0's xbuf stores before release
                if (tid == 0)
                    __hip_atomic_store(&fB[r], (u32)(t + 1), __ATOMIC_RELEASE,
                                       __HIP_MEMORY_SCOPE_AGENT);
            }
        }
        if (tid == 0) { losses[r0] = lacc0; losses[r0 + 1] = lacc1; }
    }
}

__global__ void reduce_loss(const double* __restrict__ losses, float* __restrict__ out) {
    int lane = threadIdx.x; // 64 threads, 1 wave
    double v = losses[lane];
#pragma unroll
    for (int s = 32; s >= 1; s >>= 1) v += __shfl_down(v, s);
    if (lane == 0) out[0] = (float)(v * (1.0 / ((double)BATCH * (double)TSTEPS)));
}

extern "C" void kernel_launch(void* const* d_in, const int* in_sizes, int n_in,
                              void* d_out, int out_size, void* d_ws, size_t ws_size,
                              hipStream_t stream) {
    const int*   tokens  = (const int*)d_in[0];   // (64, 512) int32
    const float* initial = (const float*)d_in[1]; // (1024,)
    const float* embed   = (const float*)d_in[2]; // (128, 128)
    const float* ff      = (const float*)d_in[3]; // (6, 1024, 1024)
    const float* head    = (const float*)d_in[4]; // (128, 128)
    const float* thrl    = (const float*)d_in[5]; // (6, 1024)

    char* ws = (char*)d_ws;
    u64*    ffb    = (u64*)ws;
    u64*    eb     = (u64*)(ws + OFF_EB);
    u64*    hb     = (u64*)(ws + OFF_HB);
    double* losses = (double*)(ws + OFF_LOSS);
    u64*    xbuf   = (u64*)(ws + OFF_XBUF);
    u64*    mbuf   = (u64*)(ws + OFF_MBUF);
    u32*    fAf    = (u32*)(ws + OFF_FA);
    u32*    fBf    = (u32*)(ws + OFF_FB);

    // reset handshake flags every call (harness does not re-poison ws)
    hipMemsetAsync(ws + OFF_FA, 0, 512, stream);

    pack_ff<<<384, 256, 0, stream>>>(ff, ffb);
    pack_small<<<1, 256, 0, stream>>>(embed, head, eb, hb);
    brnn_pipe<<<BATCH, HALF, 0, stream>>>(tokens, initial, thrl, ffb, eb, hb,
                                          xbuf, mbuf, fAf, fBf, losses);
    reduce_loss<<<1, 64, 0, stream>>>(losses, (float*)d_out);
}

// Round 3
// 6993.326 us; speedup vs baseline: 1.1591x; 1.1591x over previous
//
#include <hip/hip_runtime.h>
#include <stdint.h>

typedef unsigned long long u64;

#define VOCAB 128
#define RD 128
#define DM 1024
#define NFF 6
#define BATCH 64
#define TSTEPS 512

// ---------------------------------------------------------------------------
// ws layout:
//   [0, 786432)          ffbits  [i][w][j] u64   (i<6, w<16, j<1024)
//   [786432, +2048)      ebits   [v][2]    u64   (v<128)
//   [788480, +2048)      headb   [v][2]    u64   (v<128)
//   [790528, +512)       losses  [64]      double
// ---------------------------------------------------------------------------

// Pack ff sign bits: bit b of word (i,w,j) = (ff[i][w*64+b][j] < 0)  (1 => -1)
__global__ void pack_ff(const float* __restrict__ ff, u64* __restrict__ ffb) {
    int wid  = blockIdx.x * (blockDim.x >> 6) + (threadIdx.x >> 6); // wave id, 0..1535
    int lane = threadIdx.x & 63;
    int jt = wid & 15;
    int w  = (wid >> 4) & 15;
    int i  = wid >> 8;
    int j  = jt * 64 + lane;
    const float* src = ff + ((size_t)(i * DM) + w * 64) * DM + j;
    u64 word = 0;
#pragma unroll
    for (int b = 0; b < 64; ++b) {
        float v = src[(size_t)b * DM];
        word |= (u64)(v < 0.0f) << b;
    }
    ffb[((i * 16 + w) << 10) + j] = word;
}

// Pack embed rows and head columns (tiny).
__global__ void pack_small(const float* __restrict__ emb, const float* __restrict__ head,
                           u64* __restrict__ eb, u64* __restrict__ hb) {
    int tid = threadIdx.x; // 0..255
    if (tid < 128) {
        int v = tid;
        for (int wd = 0; wd < 2; ++wd) {
            u64 word = 0;
            for (int l = 0; l < 64; ++l)
                word |= (u64)(emb[v * RD + wd * 64 + l] < 0.0f) << l;
            eb[v * 2 + wd] = word;
        }
    } else {
        int v = tid - 128;
        for (int wd = 0; wd < 2; ++wd) {
            u64 word = 0;
            for (int l = 0; l < 64; ++l)
                word |= (u64)(head[(wd * 64 + l) * VOCAB + v] < 0.0f) << l;
            hb[v * 2 + wd] = word;
        }
    }
}

// Main recurrent kernel: one block per batch row, thread j owns column j.
// All 6 layers' packed weight columns (96 u64 = 192 VGPRs) are pinned in
// registers via empty volatile-asm: the compiler cannot rematerialize or
// sink an asm result, so the weights stay resident across the whole t-loop.
// __launch_bounds__(1024, 4): 4 waves/SIMD -> 512-reg budget (256 arch + AGPR).
__global__ void __launch_bounds__(1024, 4)
brnn_main(const int* __restrict__ tokens,
          const float* __restrict__ initial_lat,
          const float* __restrict__ thr_lat,
          const u64* __restrict__ ffb,
          const u64* __restrict__ eb,
          const u64* __restrict__ hb,
          double* __restrict__ losses) {
    const int b    = blockIdx.x;
    const int tid  = threadIdx.x;
    const int lane = tid & 63;
    const int wv   = tid >> 6;

    __shared__ __align__(16) u64 hbuf[2][16];

    // --- load packed ff columns into registers, pinned against remat ---
    u64 fr[NFF][16];
#pragma unroll
    for (int i = 0; i < NFF; ++i)
#pragma unroll
        for (int w = 0; w < 16; ++w) {
            u64 v = ffb[((i * 16 + w) << 10) + tid];
            asm volatile("" : "+v"(v));   // opaque: must stay in a register
            fr[i][w] = v;
        }

    // thresholds -> popcount cutoffs:  bit(-1) <=> pre < thr  <=>  acc >= cthr
    int cthr[NFF];
#pragma unroll
    for (int i = 0; i < NFF; ++i) {
        int thr = (int)rintf(thr_lat[i * DM + tid]); // round-half-even == jnp.round
        cthr[i] = ((DM - thr) >> 1) + 1;
    }

    // head bits (used by wave 0 only; loaded uniformly to avoid divergence,
    // pinned so they aren't re-fetched every step)
    u64 h0a = hb[lane * 2 + 0];
    u64 h0b = hb[lane * 2 + 1];
    u64 h1a = hb[(lane + 64) * 2 + 0];
    u64 h1b = hb[(lane + 64) * 2 + 1];
    asm volatile("" : "+v"(h0a), "+v"(h0b), "+v"(h1a), "+v"(h1b));

    // --- init h = sign(initial_lat), into buffer 0 ---
    {
        u64 m = __ballot(initial_lat[tid] < 0.0f);
        if (lane == 0) hbuf[0][wv] = m;
    }
    __syncthreads();

    const int* toks = tokens + b * TSTEPS;
    double lacc = 0.0;
    int p = 0; // current h buffer (always 0 at step boundaries: 6 flips/step)

    for (int t = 0; t < TSTEPS; ++t) {
        int tok = toks[t]; // uniform -> scalar load

        // prefetch embed bits for the end-of-step splice (hides under 6 layers)
        u64 enew = 0;
        if (wv == 0 && lane < 2) enew = eb[tok * 2 + lane];

        // --- 6 binary FF layers ---
#pragma unroll
        for (int i = 0; i < NFF; ++i) {
            const ulonglong2* hp = (const ulonglong2*)hbuf[p];
            int acc = 0;
#pragma unroll
            for (int q = 0; q < 8; ++q) {
                ulonglong2 hv = hp[q]; // broadcast ds_read_b128
                acc += __popcll(hv.x ^ fr[i][2 * q]) + __popcll(hv.y ^ fr[i][2 * q + 1]);
            }
            u64 m = __ballot(acc >= cthr[i]);
            if (lane == 0) hbuf[p ^ 1][wv] = m;
            p ^= 1;
            __syncthreads();
        }

        // --- head + log-softmax + loss + embed splice (wave 0 only) ---
        if (wv == 0) {
            u64 r0 = hbuf[p][14], r1 = hbuf[p][15];
            int d0 = 128 - 2 * (__popcll(r0 ^ h0a) + __popcll(r1 ^ h0b));
            int d1 = 128 - 2 * (__popcll(r0 ^ h1a) + __popcll(r1 ^ h1b));
            float l0 = (float)d0 * (1.0f / 16.0f);
            float l1 = (float)d1 * (1.0f / 16.0f);
            float mx = fmaxf(l0, l1);
#pragma unroll
            for (int s = 32; s >= 1; s >>= 1) mx = fmaxf(mx, __shfl_xor(mx, s));
            float se = __expf(l0 - mx) + __expf(l1 - mx);
#pragma unroll
            for (int s = 32; s >= 1; s >>= 1) se += __shfl_xor(se, s);
            int   tl   = tok & 63;
            float la   = __shfl(l0, tl);
            float lb   = __shfl(l1, tl);
            float ltok = (tok >> 6) ? lb : la;
            lacc += (double)(mx + __logf(se) - ltok);
            // splice x_new read-part = sign(embed[tok]) into words 14,15
            if (lane < 2) hbuf[p][14 + lane] = enew;
        }
        __syncthreads();
    }

    if (tid == 0) losses[b] = lacc;
}

__global__ void reduce_loss(const double* __restrict__ losses, float* __restrict__ out) {
    int lane = threadIdx.x; // 64 threads, 1 wave
    double v = losses[lane];
#pragma unroll
    for (int s = 32; s >= 1; s >>= 1) v += __shfl_down(v, s);
    if (lane == 0) out[0] = (float)(v * (1.0 / ((double)BATCH * (double)TSTEPS)));
}

extern "C" void kernel_launch(void* const* d_in, const int* in_sizes, int n_in,
                              void* d_out, int out_size, void* d_ws, size_t ws_size,
                              hipStream_t stream) {
    const int*   tokens  = (const int*)d_in[0];   // (64, 512) int32
    const float* initial = (const float*)d_in[1]; // (1024,)
    const float* embed   = (const float*)d_in[2]; // (128, 128)
    const float* ff      = (const float*)d_in[3]; // (6, 1024, 1024)
    const float* head    = (const float*)d_in[4]; // (128, 128)
    const float* thrl    = (const float*)d_in[5]; // (6, 1024)

    char* ws = (char*)d_ws;
    u64*    ffb    = (u64*)ws;                      // 786432 B
    u64*    eb     = (u64*)(ws + 786432);           // 2048 B
    u64*    hb     = (u64*)(ws + 786432 + 2048);    // 2048 B
    double* losses = (double*)(ws + 786432 + 4096); // 512 B

    pack_ff<<<384, 256, 0, stream>>>(ff, ffb);
    pack_small<<<1, 256, 0, stream>>>(embed, head, eb, hb);
    brnn_main<<<BATCH, 1024, 0, stream>>>(tokens, initial, thrl, ffb, eb, hb, losses);
    reduce_loss<<<1, 64, 0, stream>>>(losses, (float*)d_out);
}